// Round 3
// baseline (656.573 us; speedup 1.0000x reference)
//
#include <hip/hip_runtime.h>
#include <stdint.h>

#define B_ 16
#define C_ 512
#define T_ 4096
#define H_ 8
#define D_ 64
#define SCALE_ 0.125f
#define EPS_ 1e-5f

using ushortT = unsigned short;
using ushort8 = __attribute__((ext_vector_type(8))) unsigned short;
using short8  = __attribute__((ext_vector_type(8))) short;
using floatx4 = __attribute__((ext_vector_type(4))) float;

__device__ __forceinline__ float bf2f(ushortT u) {
  union { unsigned int i; float f; } x; x.i = ((unsigned int)u) << 16; return x.f;
}
__device__ __forceinline__ ushortT f2bf(float f) {
  union { float f; unsigned int i; } x; x.f = f;
  unsigned int r = x.i + 0x7fffu + ((x.i >> 16) & 1u);
  return (ushortT)(r >> 16);
}

// ---------------- fp32 -> bf16 convert (weights) ----------------
__global__ __launch_bounds__(256) void cvt_f32_bf16(const float* __restrict__ src,
                                                    ushortT* __restrict__ dst, int n4) {
  int i = blockIdx.x * 256 + threadIdx.x;
  if (i >= n4) return;
  floatx4 v = *(const floatx4*)(src + (size_t)i * 4);
  unsigned int p0 = (unsigned int)f2bf(v[0]) | ((unsigned int)f2bf(v[1]) << 16);
  unsigned int p1 = (unsigned int)f2bf(v[2]) | ((unsigned int)f2bf(v[3]) << 16);
  *(unsigned long long*)(dst + (size_t)i * 4) =
      (unsigned long long)p0 | ((unsigned long long)p1 << 32);
}

// ---------------- zero init (ct + stats, contiguous) ----------------
__global__ void zero_f32(float* p, int n4) {
  int i = blockIdx.x * 256 + threadIdx.x;
  if (i < n4) ((floatx4*)p)[i] = (floatx4){0.f, 0.f, 0.f, 0.f};
}

// ---------------- transpose x[b][c][t] (fp32) -> xT[b][t][c] (bf16) ----------------
__global__ __launch_bounds__(256) void transpose_x(const float* __restrict__ x,
                                                   ushortT* __restrict__ xT) {
  __shared__ ushortT tile[64][65];
  int b = blockIdx.z;
  int t0 = blockIdx.x * 64, c0 = blockIdx.y * 64;
  const float* xb = x + (size_t)b * C_ * T_;
  ushortT* xTb = xT + (size_t)b * T_ * C_;
  for (int i = threadIdx.x; i < 4096; i += 256) {
    int cc = i >> 6, tt = i & 63;
    tile[cc][tt] = f2bf(xb[(size_t)(c0 + cc) * T_ + t0 + tt]);
  }
  __syncthreads();
  for (int i = threadIdx.x; i < 4096; i += 256) {
    int tt = i >> 6, cc = i & 63;
    xTb[(size_t)(t0 + tt) * C_ + c0 + cc] = tile[cc][tt];
  }
}

// ---------------- bf16 GEMM: C[m][n] = sum_k A[m][k]*Bt[n][k] (+bias[m]) ----------------
// grid: (N/128, M/128, batch), block 256. 128x128 tile, BK=32, 16x16x32 MFMA.
// out_f32: 0 -> Cc is bf16 (ushort), 1 -> Cc is fp32 (float). bias is fp32 or null.
__global__ __launch_bounds__(256) void gemm_bt(
    const ushortT* __restrict__ A, const ushortT* __restrict__ Bt,
    void* __restrict__ Cc, const float* __restrict__ bias,
    int K, int lda, int ldb, int ldc, int out_f32,
    unsigned long long bsA, unsigned long long bsB, unsigned long long bsC) {
  __shared__ ushortT As[128 * 32];
  __shared__ ushortT Bs[128 * 32];
  const int b = blockIdx.z;
  A += (size_t)b * bsA; Bt += (size_t)b * bsB;
  const int m0 = blockIdx.y * 128, n0 = blockIdx.x * 128;
  const int tid = threadIdx.x;
  const int w = tid >> 6, l = tid & 63;
  const int wm = (w >> 1) * 64, wn = (w & 1) * 64;
  const int quad = l >> 4, ln = l & 15;
  floatx4 acc[4][4];
#pragma unroll
  for (int i = 0; i < 4; i++)
#pragma unroll
    for (int j = 0; j < 4; j++) acc[i][j] = (floatx4){0.f, 0.f, 0.f, 0.f};

  for (int kb = 0; kb < K; kb += 32) {
#pragma unroll
    for (int i = 0; i < 2; ++i) {
      int ci = i * 256 + tid;
      int row = ci >> 2, col = (ci & 3) << 3;
      *(uint4*)(&As[row * 32 + col]) = *(const uint4*)(&A[(size_t)(m0 + row) * lda + kb + col]);
      *(uint4*)(&Bs[row * 32 + col]) = *(const uint4*)(&Bt[(size_t)(n0 + row) * ldb + kb + col]);
    }
    __syncthreads();
    short8 af[4], bfv[4];
#pragma unroll
    for (int i = 0; i < 4; i++) af[i] = *(const short8*)(&As[(wm + i * 16 + ln) * 32 + quad * 8]);
#pragma unroll
    for (int j = 0; j < 4; j++) bfv[j] = *(const short8*)(&Bs[(wn + j * 16 + ln) * 32 + quad * 8]);
#pragma unroll
    for (int i = 0; i < 4; i++)
#pragma unroll
      for (int j = 0; j < 4; j++)
        acc[i][j] = __builtin_amdgcn_mfma_f32_16x16x32_bf16(af[i], bfv[j], acc[i][j], 0, 0, 0);
    __syncthreads();
  }
  if (out_f32) {
    float* Co = (float*)Cc + (size_t)b * bsC;
#pragma unroll
    for (int i = 0; i < 4; i++)
#pragma unroll
      for (int r = 0; r < 4; r++) {
        int row = m0 + wm + i * 16 + quad * 4 + r;
        float bv = bias ? bias[row] : 0.f;
#pragma unroll
        for (int j = 0; j < 4; j++) {
          int col = n0 + wn + j * 16 + ln;
          Co[(size_t)row * ldc + col] = acc[i][j][r] + bv;
        }
      }
  } else {
    ushortT* Co = (ushortT*)Cc + (size_t)b * bsC;
#pragma unroll
    for (int i = 0; i < 4; i++)
#pragma unroll
      for (int r = 0; r < 4; r++) {
        int row = m0 + wm + i * 16 + quad * 4 + r;
        float bv = bias ? bias[row] : 0.f;
#pragma unroll
        for (int j = 0; j < 4; j++) {
          int col = n0 + wn + j * 16 + ln;
          Co[(size_t)row * ldc + col] = f2bf(acc[i][j][r] + bv);
        }
      }
  }
}

// ---------------- softmax over d (64 per head) for qT rows, * SCALE ----------------
__global__ __launch_bounds__(256) void softmax_q(ushortT* q) {
  int row = blockIdx.x * 4 + (threadIdx.x >> 6);
  int l = threadIdx.x & 63;
  ushortT* p = q + (size_t)row * 512 + l * 8;
  ushort8 v = *(const ushort8*)p;
  float f[8];
  float mx = -1e30f;
#pragma unroll
  for (int j = 0; j < 8; j++) { f[j] = bf2f(v[j]); mx = fmaxf(mx, f[j]); }
  // lanes l with l>>3 == h hold head h's 64 values; reduce within 8-lane group
#pragma unroll
  for (int off = 1; off < 8; off <<= 1) mx = fmaxf(mx, __shfl_xor(mx, off));
  float s = 0.f;
#pragma unroll
  for (int j = 0; j < 8; j++) { f[j] = expf(f[j] - mx); s += f[j]; }
#pragma unroll
  for (int off = 1; off < 8; off <<= 1) s += __shfl_xor(s, off);
  float inv = SCALE_ / s;
  ushort8 o;
#pragma unroll
  for (int j = 0; j < 8; j++) o[j] = f2bf(f[j] * inv);
  *(ushort8*)p = o;
}

// ---------------- softmax over t (4096, contiguous) for k rows of kv ----------------
__global__ __launch_bounds__(256) void softmax_k(ushortT* kv) {
  int b = blockIdx.x >> 9, o = blockIdx.x & 511;
  ushortT* p = kv + ((size_t)b * 1024 + o) * T_;
  int tid = threadIdx.x, w = tid >> 6, l = tid & 63;
  float f[16];
  float mx = -1e30f;
#pragma unroll
  for (int c = 0; c < 2; ++c) {
    ushort8 v = *(const ushort8*)(p + (size_t)(c * 256 + tid) * 8);
#pragma unroll
    for (int j = 0; j < 8; j++) { f[c * 8 + j] = bf2f(v[j]); mx = fmaxf(mx, f[c * 8 + j]); }
  }
#pragma unroll
  for (int off = 1; off < 64; off <<= 1) mx = fmaxf(mx, __shfl_xor(mx, off));
  __shared__ float red[4], red2[4];
  if (l == 0) red[w] = mx;
  __syncthreads();
  mx = fmaxf(fmaxf(red[0], red[1]), fmaxf(red[2], red[3]));
  float s = 0.f;
#pragma unroll
  for (int i = 0; i < 16; i++) { f[i] = expf(f[i] - mx); s += f[i]; }
#pragma unroll
  for (int off = 1; off < 64; off <<= 1) s += __shfl_xor(s, off);
  if (l == 0) red2[w] = s;
  __syncthreads();
  s = red2[0] + red2[1] + red2[2] + red2[3];
  float inv = 1.f / s;
#pragma unroll
  for (int c = 0; c < 2; ++c) {
    ushort8 o;
#pragma unroll
    for (int j = 0; j < 8; j++) o[j] = f2bf(f[c * 8 + j] * inv);
    *(ushort8*)(p + (size_t)(c * 256 + tid) * 8) = o;
  }
}

// ---------------- context: ct[b][h][e][d] += sum_t v[e][t]*k_sm[d][t] (split-K over t) ----------------
// grid (8 slices, 8 h, 16 b), block 64 (one wave). M=e(64), N=d(64), K=512 per slice.
__global__ __launch_bounds__(64) void context_kv(const ushortT* __restrict__ kv,
                                                 float* __restrict__ ct) {
  __shared__ ushortT Vs[64 * 32];
  __shared__ ushortT Ks[64 * 32];
  const int slice = blockIdx.x, h = blockIdx.y, b = blockIdx.z;
  const int t0 = slice * 512;
  const ushortT* vrow = kv + ((size_t)b * 1024 + 512 + h * 64) * T_;
  const ushortT* krow = kv + ((size_t)b * 1024 + h * 64) * T_;
  const int tid = threadIdx.x, quad = tid >> 4, ln = tid & 15;
  floatx4 acc[4][4];
#pragma unroll
  for (int i = 0; i < 4; i++)
#pragma unroll
    for (int j = 0; j < 4; j++) acc[i][j] = (floatx4){0.f, 0.f, 0.f, 0.f};
  for (int kb = 0; kb < 512; kb += 32) {
#pragma unroll
    for (int i = 0; i < 4; ++i) {
      int ci = i * 64 + tid;
      int row = ci >> 2, col = (ci & 3) << 3;
      *(uint4*)(&Vs[row * 32 + col]) = *(const uint4*)(&vrow[(size_t)row * T_ + t0 + kb + col]);
      *(uint4*)(&Ks[row * 32 + col]) = *(const uint4*)(&krow[(size_t)row * T_ + t0 + kb + col]);
    }
    __syncthreads();
    short8 af[4], bfv[4];
#pragma unroll
    for (int i = 0; i < 4; i++) af[i] = *(const short8*)(&Vs[(i * 16 + ln) * 32 + quad * 8]);
#pragma unroll
    for (int j = 0; j < 4; j++) bfv[j] = *(const short8*)(&Ks[(j * 16 + ln) * 32 + quad * 8]);
#pragma unroll
    for (int i = 0; i < 4; i++)
#pragma unroll
      for (int j = 0; j < 4; j++)
        acc[i][j] = __builtin_amdgcn_mfma_f32_16x16x32_bf16(af[i], bfv[j], acc[i][j], 0, 0, 0);
    __syncthreads();
  }
  float* ctbh = ct + (size_t)(b * 8 + h) * 4096;
#pragma unroll
  for (int i = 0; i < 4; i++)
#pragma unroll
    for (int r = 0; r < 4; r++) {
      int e = i * 16 + quad * 4 + r;
#pragma unroll
      for (int j = 0; j < 4; j++) {
        int d = j * 16 + ln;
        atomicAdd(&ctbh[e * 64 + d], acc[i][j][r]);
      }
    }
}

// ---------------- attT[b][t][h*64+e] = sum_d qT[t][h*64+d] * ct[e][d] (IN-PLACE on qT) ----------------
// grid (64 t-tiles, 8 h, 16 b), block 64. M=t(64), N=e(64), K=d(64).
__global__ __launch_bounds__(64) void attn_out(const ushortT* __restrict__ qT,
                                               const float* __restrict__ ct,
                                               ushortT* __restrict__ attT) {
  __shared__ ushortT Qs[64 * 64];
  __shared__ ushortT Cs[64 * 64];
  const int t0 = blockIdx.x * 64, h = blockIdx.y, b = blockIdx.z;
  const int tid = threadIdx.x, quad = tid >> 4, ln = tid & 15;
  const ushortT* qb = qT + (size_t)b * T_ * 512;
  const float* ctbh = ct + (size_t)(b * 8 + h) * 4096;
#pragma unroll
  for (int i = 0; i < 8; ++i) {
    int ci = i * 64 + tid;
    int row = ci >> 3, col = (ci & 7) << 3;
    *(uint4*)(&Qs[row * 64 + col]) = *(const uint4*)(&qb[(size_t)(t0 + row) * 512 + h * 64 + col]);
  }
#pragma unroll
  for (int i = 0; i < 16; ++i) {
    int ci = i * 64 + tid;
    int off = ci * 4, row = off >> 6, col = off & 63;
    floatx4 v = *(const floatx4*)(&ctbh[off]);
    unsigned int p0 = (unsigned int)f2bf(v[0]) | ((unsigned int)f2bf(v[1]) << 16);
    unsigned int p1 = (unsigned int)f2bf(v[2]) | ((unsigned int)f2bf(v[3]) << 16);
    *(unsigned long long*)(&Cs[row * 64 + col]) =
        (unsigned long long)p0 | ((unsigned long long)p1 << 32);
  }
  __syncthreads();
  floatx4 acc[4][4];
#pragma unroll
  for (int i = 0; i < 4; i++)
#pragma unroll
    for (int j = 0; j < 4; j++) acc[i][j] = (floatx4){0.f, 0.f, 0.f, 0.f};
#pragma unroll
  for (int kk = 0; kk < 2; ++kk) {
    short8 af[4], bfv[4];
#pragma unroll
    for (int i = 0; i < 4; i++) af[i] = *(const short8*)(&Qs[(i * 16 + ln) * 64 + kk * 32 + quad * 8]);
#pragma unroll
    for (int j = 0; j < 4; j++) bfv[j] = *(const short8*)(&Cs[(j * 16 + ln) * 64 + kk * 32 + quad * 8]);
#pragma unroll
    for (int i = 0; i < 4; i++)
#pragma unroll
      for (int j = 0; j < 4; j++)
        acc[i][j] = __builtin_amdgcn_mfma_f32_16x16x32_bf16(af[i], bfv[j], acc[i][j], 0, 0, 0);
  }
  ushortT* ob = attT + (size_t)b * T_ * 512;
#pragma unroll
  for (int i = 0; i < 4; i++)
#pragma unroll
    for (int r = 0; r < 4; r++) {
      int row = t0 + i * 16 + quad * 4 + r;
#pragma unroll
      for (int j = 0; j < 4; j++) {
        int col = h * 64 + j * 16 + ln;
        ob[(size_t)row * 512 + col] = f2bf(acc[i][j][r]);
      }
    }
}

// ---------------- GroupNorm stats (sum, sumsq per batch) over fp32 out ----------------
__global__ __launch_bounds__(256) void gn_stats(const float* __restrict__ out,
                                                float* __restrict__ stats) {
  int b = blockIdx.y;
  const float* p = out + (size_t)b * C_ * T_;
  float s = 0.f, ss = 0.f;
  for (int i = blockIdx.x * 256 + threadIdx.x; i < C_ * T_ / 8; i += 32 * 256) {
    floatx4 v0 = *(const floatx4*)(p + (size_t)i * 8);
    floatx4 v1 = *(const floatx4*)(p + (size_t)i * 8 + 4);
#pragma unroll
    for (int j = 0; j < 4; j++) { s += v0[j]; ss += v0[j] * v0[j]; }
#pragma unroll
    for (int j = 0; j < 4; j++) { s += v1[j]; ss += v1[j] * v1[j]; }
  }
#pragma unroll
  for (int off = 1; off < 64; off <<= 1) { s += __shfl_xor(s, off); ss += __shfl_xor(ss, off); }
  __shared__ float rs[4], rss[4];
  int w = threadIdx.x >> 6, l = threadIdx.x & 63;
  if (l == 0) { rs[w] = s; rss[w] = ss; }
  __syncthreads();
  if (threadIdx.x == 0) {
    s = rs[0] + rs[1] + rs[2] + rs[3];
    ss = rss[0] + rss[1] + rss[2] + rss[3];
    atomicAdd(&stats[b * 2], s);
    atomicAdd(&stats[b * 2 + 1], ss);
  }
}

// ---------------- GroupNorm apply (in-place on fp32 d_out) ----------------
__global__ __launch_bounds__(256) void gn_apply(float* __restrict__ out,
                                                const float* __restrict__ stats,
                                                const float* __restrict__ gnw,
                                                const float* __restrict__ gnb) {
  int b = blockIdx.y;
  int i = blockIdx.x * 256 + threadIdx.x;  // 8-elem chunk index
  const float invN = 1.f / (float)(C_ * T_);
  float mean = stats[b * 2] * invN;
  float var = stats[b * 2 + 1] * invN - mean * mean;
  float inv = rsqrtf(var + EPS_);
  int c = i >> 9;  // 4096/8 = 512 chunks per channel
  float wv = gnw[c] * inv, bv = gnb[c];
  float* p = out + (size_t)b * C_ * T_ + (size_t)i * 8;
  floatx4 v0 = *(const floatx4*)p;
  floatx4 v1 = *(const floatx4*)(p + 4);
#pragma unroll
  for (int j = 0; j < 4; j++) v0[j] = (v0[j] - mean) * wv + bv;
#pragma unroll
  for (int j = 0; j < 4; j++) v1[j] = (v1[j] - mean) * wv + bv;
  *(floatx4*)p = v0;
  *(floatx4*)(p + 4) = v1;
}

extern "C" void kernel_launch(void* const* d_in, const int* in_sizes, int n_in,
                              void* d_out, int out_size, void* d_ws, size_t ws_size,
                              hipStream_t stream) {
  (void)in_sizes; (void)n_in; (void)out_size; (void)ws_size;
  const float* x    = (const float*)d_in[0];
  const float* Wqkv = (const float*)d_in[1];
  const float* Wout = (const float*)d_in[2];
  const float* bout = (const float*)d_in[3];
  const float* gnw  = (const float*)d_in[4];
  const float* gnb  = (const float*)d_in[5];
  float* out = (float*)d_out;

  // ws layout (132 MB):
  //   xT    bf16 [b][t][512]      @ 0          (64 MB)
  //   qT    bf16 [b][t][512]      @ 64M        (64 MB)   attn_out in-place -> attT
  //   Wq_bf bf16 [1536][512]      @ 128M       (1.5 MB)
  //   Wo_bf bf16 [512][512]       @ 129.5M     (0.5 MB)
  //   ct    fp32 [16][8][64][64]  @ 130M       (2 MB)
  //   stats fp32 [32]             @ 132M       (contiguous after ct)
  // kv bf16 [b][1024][t] (128 MB) lives in d_out (134 MB fp32), dead before the
  // final out-projection GEMM overwrites d_out.
  char* ws = (char*)d_ws;
  ushortT* xT   = (ushortT*)(ws);
  ushortT* qT   = (ushortT*)(ws + 67108864);
  ushortT* Wqbf = (ushortT*)(ws + 134217728);
  ushortT* Wobf = (ushortT*)(ws + 135790592);
  float*   ct   = (float*)(ws + 136314880);
  float* stats  = (float*)(ws + 138412032);
  ushortT* kv   = (ushortT*)d_out;
  ushortT* attT = qT;  // in-place

  cvt_f32_bf16<<<768, 256, 0, stream>>>(Wqkv, Wqbf, 196608);   // 1536*512/4
  cvt_f32_bf16<<<256, 256, 0, stream>>>(Wout, Wobf, 65536);    // 512*512/4
  // zero ct + stats: (2097152+128)/16 = 131080 float4
  zero_f32<<<513, 256, 0, stream>>>(ct, 131080);

  transpose_x<<<dim3(64, 8, 16), 256, 0, stream>>>(x, xT);

  // kv[b][o'][t] = W_qkv[512+o'][:] . xT[b][t][:]   (M=1024, N=4096, K=512)
  gemm_bt<<<dim3(32, 8, 16), 256, 0, stream>>>(
      Wqbf + 512 * 512, xT, kv, nullptr, 512, 512, 512, 4096, 0,
      0ULL, (unsigned long long)(T_ * 512), (unsigned long long)(1024 * T_));

  // qT[b][t][o] = xT[b][t][:] . W_qkv[o][:]         (M=4096, N=512, K=512)
  gemm_bt<<<dim3(4, 32, 16), 256, 0, stream>>>(
      xT, Wqbf, qT, nullptr, 512, 512, 512, 512, 0,
      (unsigned long long)(T_ * 512), 0ULL, (unsigned long long)(T_ * 512));

  softmax_q<<<16384, 256, 0, stream>>>(qT);
  softmax_k<<<8192, 256, 0, stream>>>(kv);

  context_kv<<<dim3(8, 8, 16), 64, 0, stream>>>(kv, ct);
  attn_out<<<dim3(64, 8, 16), 64, 0, stream>>>(qT, ct, attT);

  // out[b][c][t] = W_out[c][:] . attT[b][t][:] + b_out[c]   (fp32 out, M=512, N=4096, K=512)
  gemm_bt<<<dim3(32, 4, 16), 256, 0, stream>>>(
      Wobf, attT, out, bout, 512, 512, 512, 4096, 1,
      0ULL, (unsigned long long)(T_ * 512), (unsigned long long)(512 * T_));

  gn_stats<<<dim3(32, 16), 256, 0, stream>>>(out, stats);
  gn_apply<<<dim3(1024, 16), 256, 0, stream>>>(out, stats, gnw, gnb);
}

// Round 4
// 642.836 us; speedup vs baseline: 1.0214x; 1.0214x over previous
//
#include <hip/hip_runtime.h>
#include <stdint.h>

#define B_ 16
#define C_ 512
#define T_ 4096
#define H_ 8
#define D_ 64
#define SCALE_ 0.125f
#define EPS_ 1e-5f

using ushortT = unsigned short;
using ushort8 = __attribute__((ext_vector_type(8))) unsigned short;
using short8  = __attribute__((ext_vector_type(8))) short;
using floatx4 = __attribute__((ext_vector_type(4))) float;

__device__ __forceinline__ float bf2f(ushortT u) {
  union { unsigned int i; float f; } x; x.i = ((unsigned int)u) << 16; return x.f;
}
__device__ __forceinline__ ushortT f2bf(float f) {
  union { float f; unsigned int i; } x; x.f = f;
  unsigned int r = x.i + 0x7fffu + ((x.i >> 16) & 1u);
  return (ushortT)(r >> 16);
}

// async 16B global->LDS (direct DMA, no VGPR round-trip). LDS dest is
// wave-uniform base + lane*16 (m104/m108 constraint) -> pass wave base.
#define GLD16(gp, lp)                                                          \
  __builtin_amdgcn_global_load_lds(                                            \
      (const __attribute__((address_space(1))) unsigned int*)(gp),             \
      (__attribute__((address_space(3))) unsigned int*)(lp), 16, 0, 0)

// ---------------- fp32 -> bf16 convert (weights) ----------------
__global__ __launch_bounds__(256) void cvt_f32_bf16(const float* __restrict__ src,
                                                    ushortT* __restrict__ dst, int n4) {
  int i = blockIdx.x * 256 + threadIdx.x;
  if (i >= n4) return;
  floatx4 v = *(const floatx4*)(src + (size_t)i * 4);
  unsigned int p0 = (unsigned int)f2bf(v[0]) | ((unsigned int)f2bf(v[1]) << 16);
  unsigned int p1 = (unsigned int)f2bf(v[2]) | ((unsigned int)f2bf(v[3]) << 16);
  *(unsigned long long*)(dst + (size_t)i * 4) =
      (unsigned long long)p0 | ((unsigned long long)p1 << 32);
}

// ---------------- zero init (ct + stats, contiguous) ----------------
__global__ void zero_f32(float* p, int n4) {
  int i = blockIdx.x * 256 + threadIdx.x;
  if (i < n4) ((floatx4*)p)[i] = (floatx4){0.f, 0.f, 0.f, 0.f};
}

// ---------------- transpose x[b][c][t] (fp32) -> xT[b][t][c] (bf16) ----------------
__global__ __launch_bounds__(256) void transpose_x(const float* __restrict__ x,
                                                   ushortT* __restrict__ xT) {
  __shared__ ushortT tile[64][65];
  int b = blockIdx.z;
  int t0 = blockIdx.x * 64, c0 = blockIdx.y * 64;
  const float* xb = x + (size_t)b * C_ * T_;
  ushortT* xTb = xT + (size_t)b * T_ * C_;
  for (int i = threadIdx.x; i < 4096; i += 256) {
    int cc = i >> 6, tt = i & 63;
    tile[cc][tt] = f2bf(xb[(size_t)(c0 + cc) * T_ + t0 + tt]);
  }
  __syncthreads();
  for (int i = threadIdx.x; i < 4096; i += 256) {
    int tt = i >> 6, cc = i & 63;
    xTb[(size_t)(t0 + tt) * C_ + c0 + cc] = tile[cc][tt];
  }
}

// ---------------- bf16 GEMM: C[m][n] = sum_k A[m][k]*Bt[n][k] (+bias[m]) ----------------
// grid: (N/128, M/128, batch), block 256. 128x128 tile, BK=32, 16x16x32 MFMA.
// Staging via global_load_lds width=16 (m97 ladder step: 517->874 TF).
// LDS byte offset of chunk ci is exactly 16*ci -> wave-uniform base + lane*16. 
// out_f32: 0 -> Cc is bf16 (ushort), 1 -> Cc is fp32 (float). bias is fp32 or null.
__global__ __launch_bounds__(256) void gemm_bt(
    const ushortT* __restrict__ A, const ushortT* __restrict__ Bt,
    void* __restrict__ Cc, const float* __restrict__ bias,
    int K, int lda, int ldb, int ldc, int out_f32,
    unsigned long long bsA, unsigned long long bsB, unsigned long long bsC) {
  __shared__ ushortT As[128 * 32];
  __shared__ ushortT Bs[128 * 32];
  const int b = blockIdx.z;
  A += (size_t)b * bsA; Bt += (size_t)b * bsB;
  const int m0 = blockIdx.y * 128, n0 = blockIdx.x * 128;
  const int tid = threadIdx.x;
  const int w = tid >> 6, l = tid & 63;
  const int wm = (w >> 1) * 64, wn = (w & 1) * 64;
  const int quad = l >> 4, ln = l & 15;
  floatx4 acc[4][4];
#pragma unroll
  for (int i = 0; i < 4; i++)
#pragma unroll
    for (int j = 0; j < 4; j++) acc[i][j] = (floatx4){0.f, 0.f, 0.f, 0.f};

  for (int kb = 0; kb < K; kb += 32) {
#pragma unroll
    for (int i = 0; i < 2; ++i) {
      int wci = i * 256 + (tid & 192);   // wave-uniform chunk base
      int ci  = wci + (tid & 63);        // this lane's chunk
      int row = ci >> 2, col = (ci & 3) << 3;
      GLD16(&A[(size_t)(m0 + row) * lda + kb + col], &As[wci * 8]);
      GLD16(&Bt[(size_t)(n0 + row) * ldb + kb + col], &Bs[wci * 8]);
    }
    __syncthreads();   // drains vmcnt (global_load_lds) before LDS reads
    short8 af[4], bfv[4];
#pragma unroll
    for (int i = 0; i < 4; i++) af[i] = *(const short8*)(&As[(wm + i * 16 + ln) * 32 + quad * 8]);
#pragma unroll
    for (int j = 0; j < 4; j++) bfv[j] = *(const short8*)(&Bs[(wn + j * 16 + ln) * 32 + quad * 8]);
#pragma unroll
    for (int i = 0; i < 4; i++)
#pragma unroll
      for (int j = 0; j < 4; j++)
        acc[i][j] = __builtin_amdgcn_mfma_f32_16x16x32_bf16(af[i], bfv[j], acc[i][j], 0, 0, 0);
    __syncthreads();
  }
  if (out_f32) {
    float* Co = (float*)Cc + (size_t)b * bsC;
#pragma unroll
    for (int i = 0; i < 4; i++)
#pragma unroll
      for (int r = 0; r < 4; r++) {
        int row = m0 + wm + i * 16 + quad * 4 + r;
        float bv = bias ? bias[row] : 0.f;
#pragma unroll
        for (int j = 0; j < 4; j++) {
          int col = n0 + wn + j * 16 + ln;
          Co[(size_t)row * ldc + col] = acc[i][j][r] + bv;
        }
      }
  } else {
    ushortT* Co = (ushortT*)Cc + (size_t)b * bsC;
#pragma unroll
    for (int i = 0; i < 4; i++)
#pragma unroll
      for (int r = 0; r < 4; r++) {
        int row = m0 + wm + i * 16 + quad * 4 + r;
        float bv = bias ? bias[row] : 0.f;
#pragma unroll
        for (int j = 0; j < 4; j++) {
          int col = n0 + wn + j * 16 + ln;
          Co[(size_t)row * ldc + col] = f2bf(acc[i][j][r] + bv);
        }
      }
  }
}

// ---------------- softmax over d (64 per head) for qT rows, * SCALE ----------------
__global__ __launch_bounds__(256) void softmax_q(ushortT* q) {
  int row = blockIdx.x * 4 + (threadIdx.x >> 6);
  int l = threadIdx.x & 63;
  ushortT* p = q + (size_t)row * 512 + l * 8;
  ushort8 v = *(const ushort8*)p;
  float f[8];
  float mx = -1e30f;
#pragma unroll
  for (int j = 0; j < 8; j++) { f[j] = bf2f(v[j]); mx = fmaxf(mx, f[j]); }
  // lanes l with l>>3 == h hold head h's 64 values; reduce within 8-lane group
#pragma unroll
  for (int off = 1; off < 8; off <<= 1) mx = fmaxf(mx, __shfl_xor(mx, off));
  float s = 0.f;
#pragma unroll
  for (int j = 0; j < 8; j++) { f[j] = expf(f[j] - mx); s += f[j]; }
#pragma unroll
  for (int off = 1; off < 8; off <<= 1) s += __shfl_xor(s, off);
  float inv = SCALE_ / s;
  ushort8 o;
#pragma unroll
  for (int j = 0; j < 8; j++) o[j] = f2bf(f[j] * inv);
  *(ushort8*)p = o;
}

// ---------------- softmax over t (4096, contiguous) for k rows of kv ----------------
__global__ __launch_bounds__(256) void softmax_k(ushortT* kv) {
  int b = blockIdx.x >> 9, o = blockIdx.x & 511;
  ushortT* p = kv + ((size_t)b * 1024 + o) * T_;
  int tid = threadIdx.x, w = tid >> 6, l = tid & 63;
  float f[16];
  float mx = -1e30f;
#pragma unroll
  for (int c = 0; c < 2; ++c) {
    ushort8 v = *(const ushort8*)(p + (size_t)(c * 256 + tid) * 8);
#pragma unroll
    for (int j = 0; j < 8; j++) { f[c * 8 + j] = bf2f(v[j]); mx = fmaxf(mx, f[c * 8 + j]); }
  }
#pragma unroll
  for (int off = 1; off < 64; off <<= 1) mx = fmaxf(mx, __shfl_xor(mx, off));
  __shared__ float red[4], red2[4];
  if (l == 0) red[w] = mx;
  __syncthreads();
  mx = fmaxf(fmaxf(red[0], red[1]), fmaxf(red[2], red[3]));
  float s = 0.f;
#pragma unroll
  for (int i = 0; i < 16; i++) { f[i] = expf(f[i] - mx); s += f[i]; }
#pragma unroll
  for (int off = 1; off < 64; off <<= 1) s += __shfl_xor(s, off);
  if (l == 0) red2[w] = s;
  __syncthreads();
  s = red2[0] + red2[1] + red2[2] + red2[3];
  float inv = 1.f / s;
#pragma unroll
  for (int c = 0; c < 2; ++c) {
    ushort8 o;
#pragma unroll
    for (int j = 0; j < 8; j++) o[j] = f2bf(f[c * 8 + j] * inv);
    *(ushort8*)(p + (size_t)(c * 256 + tid) * 8) = o;
  }
}

// ---------------- context: ct[b][h][e][d] += sum_t v[e][t]*k_sm[d][t] (split-K over t) ----------------
// grid (8 slices, 8 h, 16 b), block 64 (one wave). M=e(64), N=d(64), K=512 per slice.
__global__ __launch_bounds__(64) void context_kv(const ushortT* __restrict__ kv,
                                                 float* __restrict__ ct) {
  __shared__ ushortT Vs[64 * 32];
  __shared__ ushortT Ks[64 * 32];
  const int slice = blockIdx.x, h = blockIdx.y, b = blockIdx.z;
  const int t0 = slice * 512;
  const ushortT* vrow = kv + ((size_t)b * 1024 + 512 + h * 64) * T_;
  const ushortT* krow = kv + ((size_t)b * 1024 + h * 64) * T_;
  const int tid = threadIdx.x, quad = tid >> 4, ln = tid & 15;
  floatx4 acc[4][4];
#pragma unroll
  for (int i = 0; i < 4; i++)
#pragma unroll
    for (int j = 0; j < 4; j++) acc[i][j] = (floatx4){0.f, 0.f, 0.f, 0.f};
  for (int kb = 0; kb < 512; kb += 32) {
#pragma unroll
    for (int i = 0; i < 4; ++i) {
      int ci = i * 64 + tid;
      int row = ci >> 2, col = (ci & 3) << 3;
      *(uint4*)(&Vs[row * 32 + col]) = *(const uint4*)(&vrow[(size_t)row * T_ + t0 + kb + col]);
      *(uint4*)(&Ks[row * 32 + col]) = *(const uint4*)(&krow[(size_t)row * T_ + t0 + kb + col]);
    }
    __syncthreads();
    short8 af[4], bfv[4];
#pragma unroll
    for (int i = 0; i < 4; i++) af[i] = *(const short8*)(&Vs[(i * 16 + ln) * 32 + quad * 8]);
#pragma unroll
    for (int j = 0; j < 4; j++) bfv[j] = *(const short8*)(&Ks[(j * 16 + ln) * 32 + quad * 8]);
#pragma unroll
    for (int i = 0; i < 4; i++)
#pragma unroll
      for (int j = 0; j < 4; j++)
        acc[i][j] = __builtin_amdgcn_mfma_f32_16x16x32_bf16(af[i], bfv[j], acc[i][j], 0, 0, 0);
    __syncthreads();
  }
  float* ctbh = ct + (size_t)(b * 8 + h) * 4096;
#pragma unroll
  for (int i = 0; i < 4; i++)
#pragma unroll
    for (int r = 0; r < 4; r++) {
      int e = i * 16 + quad * 4 + r;
#pragma unroll
      for (int j = 0; j < 4; j++) {
        int d = j * 16 + ln;
        atomicAdd(&ctbh[e * 64 + d], acc[i][j][r]);
      }
    }
}

// ---------------- attT[b][t][h*64+e] = sum_d qT[t][h*64+d] * ct[e][d] (IN-PLACE on qT) ----------------
// grid (64 t-tiles, 8 h, 16 b), block 64. M=t(64), N=e(64), K=d(64).
__global__ __launch_bounds__(64) void attn_out(const ushortT* __restrict__ qT,
                                               const float* __restrict__ ct,
                                               ushortT* __restrict__ attT) {
  __shared__ ushortT Qs[64 * 64];
  __shared__ ushortT Cs[64 * 64];
  const int t0 = blockIdx.x * 64, h = blockIdx.y, b = blockIdx.z;
  const int tid = threadIdx.x, quad = tid >> 4, ln = tid & 15;
  const ushortT* qb = qT + (size_t)b * T_ * 512;
  const float* ctbh = ct + (size_t)(b * 8 + h) * 4096;
#pragma unroll
  for (int i = 0; i < 8; ++i) {
    int ci = i * 64 + tid;
    int row = ci >> 3, col = (ci & 7) << 3;
    *(uint4*)(&Qs[row * 64 + col]) = *(const uint4*)(&qb[(size_t)(t0 + row) * 512 + h * 64 + col]);
  }
#pragma unroll
  for (int i = 0; i < 16; ++i) {
    int ci = i * 64 + tid;
    int off = ci * 4, row = off >> 6, col = off & 63;
    floatx4 v = *(const floatx4*)(&ctbh[off]);
    unsigned int p0 = (unsigned int)f2bf(v[0]) | ((unsigned int)f2bf(v[1]) << 16);
    unsigned int p1 = (unsigned int)f2bf(v[2]) | ((unsigned int)f2bf(v[3]) << 16);
    *(unsigned long long*)(&Cs[row * 64 + col]) =
        (unsigned long long)p0 | ((unsigned long long)p1 << 32);
  }
  __syncthreads();
  floatx4 acc[4][4];
#pragma unroll
  for (int i = 0; i < 4; i++)
#pragma unroll
    for (int j = 0; j < 4; j++) acc[i][j] = (floatx4){0.f, 0.f, 0.f, 0.f};
#pragma unroll
  for (int kk = 0; kk < 2; ++kk) {
    short8 af[4], bfv[4];
#pragma unroll
    for (int i = 0; i < 4; i++) af[i] = *(const short8*)(&Qs[(i * 16 + ln) * 64 + kk * 32 + quad * 8]);
#pragma unroll
    for (int j = 0; j < 4; j++) bfv[j] = *(const short8*)(&Cs[(j * 16 + ln) * 64 + kk * 32 + quad * 8]);
#pragma unroll
    for (int i = 0; i < 4; i++)
#pragma unroll
      for (int j = 0; j < 4; j++)
        acc[i][j] = __builtin_amdgcn_mfma_f32_16x16x32_bf16(af[i], bfv[j], acc[i][j], 0, 0, 0);
  }
  ushortT* ob = attT + (size_t)b * T_ * 512;
#pragma unroll
  for (int i = 0; i < 4; i++)
#pragma unroll
    for (int r = 0; r < 4; r++) {
      int row = t0 + i * 16 + quad * 4 + r;
#pragma unroll
      for (int j = 0; j < 4; j++) {
        int col = h * 64 + j * 16 + ln;
        ob[(size_t)row * 512 + col] = f2bf(acc[i][j][r]);
      }
    }
}

// ---------------- GroupNorm stats (sum, sumsq per batch) over fp32 out ----------------
__global__ __launch_bounds__(256) void gn_stats(const float* __restrict__ out,
                                                float* __restrict__ stats) {
  int b = blockIdx.y;
  const float* p = out + (size_t)b * C_ * T_;
  float s = 0.f, ss = 0.f;
  for (int i = blockIdx.x * 256 + threadIdx.x; i < C_ * T_ / 8; i += 32 * 256) {
    floatx4 v0 = *(const floatx4*)(p + (size_t)i * 8);
    floatx4 v1 = *(const floatx4*)(p + (size_t)i * 8 + 4);
#pragma unroll
    for (int j = 0; j < 4; j++) { s += v0[j]; ss += v0[j] * v0[j]; }
#pragma unroll
    for (int j = 0; j < 4; j++) { s += v1[j]; ss += v1[j] * v1[j]; }
  }
#pragma unroll
  for (int off = 1; off < 64; off <<= 1) { s += __shfl_xor(s, off); ss += __shfl_xor(ss, off); }
  __shared__ float rs[4], rss[4];
  int w = threadIdx.x >> 6, l = threadIdx.x & 63;
  if (l == 0) { rs[w] = s; rss[w] = ss; }
  __syncthreads();
  if (threadIdx.x == 0) {
    s = rs[0] + rs[1] + rs[2] + rs[3];
    ss = rss[0] + rss[1] + rss[2] + rss[3];
    atomicAdd(&stats[b * 2], s);
    atomicAdd(&stats[b * 2 + 1], ss);
  }
}

// ---------------- GroupNorm apply (in-place on fp32 d_out) ----------------
__global__ __launch_bounds__(256) void gn_apply(float* __restrict__ out,
                                                const float* __restrict__ stats,
                                                const float* __restrict__ gnw,
                                                const float* __restrict__ gnb) {
  int b = blockIdx.y;
  int i = blockIdx.x * 256 + threadIdx.x;  // 8-elem chunk index
  const float invN = 1.f / (float)(C_ * T_);
  float mean = stats[b * 2] * invN;
  float var = stats[b * 2 + 1] * invN - mean * mean;
  float inv = rsqrtf(var + EPS_);
  int c = i >> 9;  // 4096/8 = 512 chunks per channel
  float wv = gnw[c] * inv, bv = gnb[c];
  float* p = out + (size_t)b * C_ * T_ + (size_t)i * 8;
  floatx4 v0 = *(const floatx4*)p;
  floatx4 v1 = *(const floatx4*)(p + 4);
#pragma unroll
  for (int j = 0; j < 4; j++) v0[j] = (v0[j] - mean) * wv + bv;
#pragma unroll
  for (int j = 0; j < 4; j++) v1[j] = (v1[j] - mean) * wv + bv;
  *(floatx4*)p = v0;
  *(floatx4*)(p + 4) = v1;
}

extern "C" void kernel_launch(void* const* d_in, const int* in_sizes, int n_in,
                              void* d_out, int out_size, void* d_ws, size_t ws_size,
                              hipStream_t stream) {
  (void)in_sizes; (void)n_in; (void)out_size; (void)ws_size;
  const float* x    = (const float*)d_in[0];
  const float* Wqkv = (const float*)d_in[1];
  const float* Wout = (const float*)d_in[2];
  const float* bout = (const float*)d_in[3];
  const float* gnw  = (const float*)d_in[4];
  const float* gnb  = (const float*)d_in[5];
  float* out = (float*)d_out;

  // ws layout (132 MB):
  //   xT    bf16 [b][t][512]      @ 0          (64 MB)
  //   qT    bf16 [b][t][512]      @ 64M        (64 MB)   attn_out in-place -> attT
  //   Wq_bf bf16 [1536][512]      @ 128M       (1.5 MB)
  //   Wo_bf bf16 [512][512]       @ 129.5M     (0.5 MB)
  //   ct    fp32 [16][8][64][64]  @ 130M       (2 MB)
  //   stats fp32 [32]             @ 132M       (contiguous after ct)
  // kv bf16 [b][1024][t] (128 MB) lives in d_out (134 MB fp32), dead before the
  // final out-projection GEMM overwrites d_out.
  char* ws = (char*)d_ws;
  ushortT* xT   = (ushortT*)(ws);
  ushortT* qT   = (ushortT*)(ws + 67108864);
  ushortT* Wqbf = (ushortT*)(ws + 134217728);
  ushortT* Wobf = (ushortT*)(ws + 135790592);
  float*   ct   = (float*)(ws + 136314880);
  float* stats  = (float*)(ws + 138412032);
  ushortT* kv   = (ushortT*)d_out;
  ushortT* attT = qT;  // in-place

  cvt_f32_bf16<<<768, 256, 0, stream>>>(Wqkv, Wqbf, 196608);   // 1536*512/4
  cvt_f32_bf16<<<256, 256, 0, stream>>>(Wout, Wobf, 65536);    // 512*512/4
  // zero ct + stats: (2097152+128)/16 = 131080 float4
  zero_f32<<<513, 256, 0, stream>>>(ct, 131080);

  transpose_x<<<dim3(64, 8, 16), 256, 0, stream>>>(x, xT);

  // kv[b][o'][t] = W_qkv[512+o'][:] . xT[b][t][:]   (M=1024, N=4096, K=512)
  gemm_bt<<<dim3(32, 8, 16), 256, 0, stream>>>(
      Wqbf + 512 * 512, xT, kv, nullptr, 512, 512, 512, 4096, 0,
      0ULL, (unsigned long long)(T_ * 512), (unsigned long long)(1024 * T_));

  // qT[b][t][o] = xT[b][t][:] . W_qkv[o][:]         (M=4096, N=512, K=512)
  gemm_bt<<<dim3(4, 32, 16), 256, 0, stream>>>(
      xT, Wqbf, qT, nullptr, 512, 512, 512, 512, 0,
      (unsigned long long)(T_ * 512), 0ULL, (unsigned long long)(T_ * 512));

  softmax_q<<<16384, 256, 0, stream>>>(qT);
  softmax_k<<<8192, 256, 0, stream>>>(kv);

  context_kv<<<dim3(8, 8, 16), 64, 0, stream>>>(kv, ct);
  attn_out<<<dim3(64, 8, 16), 64, 0, stream>>>(qT, ct, attT);

  // out[b][c][t] = W_out[c][:] . attT[b][t][:] + b_out[c]   (fp32 out, M=512, N=4096, K=512)
  gemm_bt<<<dim3(32, 4, 16), 256, 0, stream>>>(
      Wobf, attT, out, bout, 512, 512, 512, 4096, 1,
      0ULL, (unsigned long long)(T_ * 512), (unsigned long long)(512 * T_));

  gn_stats<<<dim3(32, 16), 256, 0, stream>>>(out, stats);
  gn_apply<<<dim3(1024, 16), 256, 0, stream>>>(out, stats, gnw, gnb);
}